// Round 9
// baseline (3099.680 us; speedup 1.0000x reference)
//
#include <hip/hip_runtime.h>
#include <hip/hip_bf16.h>
#include <string.h>

// Problem constants
#define NB    4096      // batch rows
#define IND_  512       // feature dim
#define OUTD_ 512       // output dim (GEMM M, "o")
#define XCOLS 514       // P + IND
#define ND    25        // D^P
#define KTOT  12800     // IND_*ND
#define KT2   12864     // KTOT + 64 bias-tail tile

// GEMM tiling
#define BM 128
#define BN 128
#define BK 64

typedef float  f32x4  __attribute__((ext_vector_type(4)));
typedef __bf16 bf16x8 __attribute__((ext_vector_type(8)));
typedef unsigned short u16x8 __attribute__((ext_vector_type(8)));
typedef unsigned int   u32x4 __attribute__((ext_vector_type(4)));

__device__ __forceinline__ unsigned short f2bf(float f) {
  unsigned int x = __float_as_uint(f);
  return (unsigned short)((x + 0x7fffu + ((x >> 16) & 1u)) >> 16);
}

__device__ __forceinline__ float bf2f(unsigned short u) {
  return __uint_as_float(((unsigned int)u) << 16);
}

// HW packed cvt (memcpy, NOT bit_cast: __hip_bfloat162 is not trivially
// copyable -> round-4 compile failure)
__device__ __forceinline__ unsigned int pk_bf16(float a, float b) {
  float2 f; f.x = a; f.y = b;
  __hip_bfloat162 h = __float22bfloat162_rn(f);
  unsigned int u;
  __builtin_memcpy(&u, &h, 4);
  return u;
}

__device__ __forceinline__ float basis_f(float t, int j) {
  switch (j) {
    case 0: return 1.0f;
    case 1: return t;
    case 2: return t * t;
    case 3: { float r = t - 0.33f; r = r > 0.0f ? r : 0.0f; return r * r; }
    default:{ float r = t - 0.66f; r = r > 0.0f ? r : 0.0f; return r * r; }
  }
}

__device__ __forceinline__ void gload_lds16(const void* g, void* l) {
  __builtin_amdgcn_global_load_lds(
      (const __attribute__((address_space(1))) void*)g,
      (__attribute__((address_space(3))) void*)l, 16, 0, 0);
}

// ---------------------------------------------------------------------------
// prep_all: ONE dispatch replacing prep_x + prep_w + prep_tail (+counter
// zeroing).  Round-8 evidence: 4 aux dispatches cost ~86us, mostly ~10us/launch
// overhead, not traffic.  Blocks: [0,1024) prep_x | [1024,2048) prep_w |
// [2048,2176) bias tail + cnt zero.
// ---------------------------------------------------------------------------
#define PWI 32
#define PWO 8
#define PWC (PWO * ND)   // 200
#define PWP 208
#define OLS 36

__global__ __launch_bounds__(256) void prep_all_kernel(
    const float* __restrict__ x, const float* __restrict__ W,
    const float* __restrict__ bias, unsigned short* __restrict__ XFb,
    float* __restrict__ kb, unsigned short* __restrict__ Wt,
    int* __restrict__ cnt, float* __restrict__ out)
{
  __shared__ float tile[PWI * PWP];
  __shared__ unsigned short out_ls[PWC * OLS];
  const int bid = blockIdx.x;
  const int tid = threadIdx.x;

  if (bid < 1024) {
    // ---- prep_x ----
    const int b    = bid * 4 + (tid >> 6);
    const int lane = tid & 63;
    const float* xr = x + (size_t)b * XCOLS;
    const float* fp = xr + 2 + lane * 8;
    float2 a0 = *(const float2*)(fp + 0);
    float2 a1 = *(const float2*)(fp + 2);
    float2 a2 = *(const float2*)(fp + 4);
    float2 a3 = *(const float2*)(fp + 6);
    u16x8 pk;
    pk[0] = f2bf(a0.x); pk[1] = f2bf(a0.y); pk[2] = f2bf(a1.x); pk[3] = f2bf(a1.y);
    pk[4] = f2bf(a2.x); pk[5] = f2bf(a2.y); pk[6] = f2bf(a3.x); pk[7] = f2bf(a3.y);
    *reinterpret_cast<u16x8*>(XFb + (size_t)b * IND_ + lane * 8) = pk;
    float t0 = xr[0], t1 = xr[1];
    if (lane < 2) out[(size_t)b * XCOLS + lane] = (lane == 0) ? t0 : t1;
    if (lane < ND) {
      int d1 = lane / 5;
      int d2 = lane - d1 * 5;
      kb[(size_t)b * ND + lane] = basis_f(t0, d1) * basis_f(t1, d2);
    }
  } else if (bid < 2048) {
    // ---- prep_w: W[i,o,d] fp32 -> Wt[o][d*512+i] bf16 (row stride KT2) ----
    const int pw = bid - 1024;
    const int i0 = (pw & 15) * PWI;
    const int o0 = (pw >> 4) * PWO;

    for (int idx = tid; idx < PWI * (PWC / 4); idx += 256) {
      int il = idx / (PWC / 4);
      int c4 = idx - il * (PWC / 4);
      float4 v = *(const float4*)(W + ((size_t)(i0 + il) * OUTD_ + o0) * ND + c4 * 4);
      *(float4*)&tile[il * PWP + c4 * 4] = v;
    }
    __syncthreads();
    if (tid < PWC) {
      #pragma unroll
      for (int j = 0; j < PWI / 8; ++j) {
        u16x8 pk;
        #pragma unroll
        for (int jj = 0; jj < 8; ++jj)
          pk[jj] = f2bf(tile[(j * 8 + jj) * PWP + tid]);
        *reinterpret_cast<u16x8*>(&out_ls[tid * OLS + j * 8]) = pk;
      }
    }
    __syncthreads();
    for (int g = tid; g < PWC * (PWI / 8); g += 256) {
      int c  = g >> 2;
      int ig = g & 3;
      int d  = c % 25;
      int o_l = c / 25;
      u16x8 v = *reinterpret_cast<const u16x8*>(&out_ls[c * OLS + ig * 8]);
      size_t rowb = (size_t)(o0 + o_l) * KT2 + (size_t)d * IND_ + i0;
      *reinterpret_cast<u16x8*>(Wt + rowb + ig * 8) = v;
    }
  } else {
    // ---- bias K-tail + split-K counters ----
    const int pt  = bid - 2048;          // [0,128)
    const int idx = pt * 256 + tid;      // < 512*64
    const int o = idx >> 6;
    const int t = idx & 63;
    Wt[(size_t)o * KT2 + KTOT + t] =
        (t < ND) ? f2bf(bias[o * ND + t]) : (unsigned short)0;
    if (pt == 0 && tid < 128) cnt[tid] = 0;
  }
}

// ---------------------------------------------------------------------------
// gemm_fused3: C[o][b] = sum_k A[o][k]*B[b][k], K=12864 (bias in K-tail),
// split-K 4, fused kb-scale B staging, LAST-BLOCK epilogue (relu+store).
//
// Pipeline (per K-iter, ONE raw s_barrier):
//   issueA(n+1)->Als[q]  [4 DMA, oldest]   } order pinned by
//   loadB(n+2)->regs     [8 VMEM, younger] } memory-clobber asm
//   32 MFMAs on [p]
//   writeB(n+1)->Bls[q]  (regs loaded a FULL iter ago -> latency hidden)
//   s_waitcnt vmcnt(8) lgkmcnt(0); s_barrier
//     vmcnt(8): drains the 4 A-DMAs (older) while the 8 B-prefetch loads
//     stay in flight (hipBLASLt-style "never vmcnt(0)").  Tail iters that
//     skip loadB MUST use vmcnt(0) (else <=8 passes with DMAs in flight).
//   Cannot use __syncthreads(): compiler emits vmcnt(0) before s_barrier.
//
// __launch_bounds__(256,2) REQUIRED (round 6: omitting -> 64-VGPR budget ->
// scratch spills).  LDS 64KB -> 2 blocks/CU.  Swizzled granules (R3): 0 bank
// conflicts.
// ---------------------------------------------------------------------------
__global__ __launch_bounds__(256, 2) void gemm_fused3_kernel(
    const unsigned short* __restrict__ Wt, const unsigned short* __restrict__ XFb,
    const float* __restrict__ kb, float* __restrict__ P,
    float* __restrict__ out, int* __restrict__ cnt)
{
  __shared__ unsigned short Als[2][BM * BK];   // 2 x 16 KB
  __shared__ unsigned short Bls[2][BN * BK];   // 2 x 16 KB
  __shared__ int lastFlag;

  const int tid  = threadIdx.x;
  const int lane = tid & 63;
  const int w    = tid >> 6;
  const int l15  = lane & 15;
  const int quad = lane >> 4;

  // R3-proven XCD mapping: per XCD, 4 o-slices x (mostly) one bz -> A fits L2
  const int id  = blockIdx.x;
  const int xcd = id & 7;
  const int j   = id >> 3;              // [0,64)
  const int bx  = j & 3;                // o-tile
  const int pg  = xcd * 16 + (j >> 2);  // [0,128): (b-tile, split)
  const int by  = pg & 31;
  const int bz  = pg >> 5;              // split [0,4)

  const int o0 = bx * BM;
  const int b0 = by * BN;
  const int ks_begin = bz * 3200;
  const int ks_end   = (bz == 3) ? KT2 : ks_begin + 3200;
  const int N = (ks_end - ks_begin) / BK;   // 50 or 51

  const int o_off = (w & 1) * 64;
  const int b_off = (w >> 1) * 64;
  const int srow  = lane >> 3;                 // 0..7 row-in-chunk
  const int sg    = lane & 7;                  // logical granule
  const int pgr   = sg ^ srow;                 // phys (swizzled) granule
  const int scol  = pgr * 8;                   // A: swizzled SOURCE col
  const int r7    = l15 & 7;

  f32x4 acc[4][4];
  #pragma unroll
  for (int i = 0; i < 4; ++i)
    #pragma unroll
    for (int jj = 0; jj < 4; ++jj) acc[i][jj] = (f32x4)0.0f;

  u16x8 vr[2][4];
  float sc[2][4];

  auto issueA = [&](int k0, int buf) {
    #pragma unroll
    for (int c = 0; c < 4; ++c) {
      int chunk = w * 4 + c;
      int r = chunk * 8 + srow;
      gload_lds16(Wt + (size_t)(o0 + r) * KT2 + k0 + scol, &Als[buf][chunk * 512]);
    }
  };
  // exactly 8 VMEM ops on every path (vmcnt(8) accounting depends on it)
  auto loadB = [&](int k0, int s) {
    if (k0 < KTOT) {
      const int d  = k0 >> 9;
      const int i0 = k0 & 511;
      #pragma unroll
      for (int c = 0; c < 4; ++c) {
        int chunk = w * 4 + c;
        int row = chunk * 8 + srow;
        vr[s][c] = *(const u16x8*)(XFb + (size_t)(b0 + row) * IND_ + i0 + sg * 8);
        sc[s][c] = kb[(size_t)(b0 + row) * ND + d];
      }
    } else {
      #pragma unroll
      for (int c = 0; c < 4; ++c) {
        int chunk = w * 4 + c;
        int row = chunk * 8 + srow;
        u16x8 t;
        #pragma unroll
        for (int jj = 0; jj < 2; ++jj) {
          int dd  = sg * 8 + jj * 4;
          // 2 clamped f32x4 loads per c -> 8 VMEM total, then mask
          int ddc = (dd < ND) ? dd : 0;
          f32x4 kv = *(const f32x4*)(kb + (size_t)(b0 + row) * ND + ddc);
          #pragma unroll
          for (int e = 0; e < 4; ++e)
            t[jj * 4 + e] = (dd + e < ND) ? f2bf(kv[e]) : (unsigned short)0;
        }
        vr[s][c] = t;
        sc[s][c] = 1.0f;
      }
    }
  };
  auto writeB = [&](int buf, int s) {
    #pragma unroll
    for (int c = 0; c < 4; ++c) {
      int chunk = w * 4 + c;
      int row = chunk * 8 + srow;
      u32x4 rp;
      #pragma unroll
      for (int p4 = 0; p4 < 4; ++p4)
        rp[p4] = pk_bf16(bf2f(vr[s][c][2 * p4]) * sc[s][c],
                         bf2f(vr[s][c][2 * p4 + 1]) * sc[s][c]);
      *reinterpret_cast<u32x4*>(&Bls[buf][row * BK + pgr * 8]) = rp;
    }
  };

  // ---- prologue: LDS[0] <- iter0; regs[1] <- iter1 ----
  loadB(ks_begin, 0);
  asm volatile("" ::: "memory");
  issueA(ks_begin, 0);
  asm volatile("" ::: "memory");
  loadB(ks_begin + BK, 1);
  asm volatile("" ::: "memory");
  writeB(0, 0);
  asm volatile("s_waitcnt vmcnt(8) lgkmcnt(0)\n\ts_barrier" ::: "memory");

  // ---- main loop ----
  for (int n = 0; n < N; ++n) {
    const int p = n & 1;
    const int q = p ^ 1;
    const int k1 = ks_begin + (n + 1) * BK;
    const int k2 = k1 + BK;
    const bool m1 = (k1 < ks_end);
    const bool m2 = (k2 < ks_end);

    if (m1) issueA(k1, q);
    asm volatile("" ::: "memory");
    if (m2) loadB(k2, n & 1);
    asm volatile("" ::: "memory");

    #pragma unroll
    for (int ks = 0; ks < 2; ++ks) {
      bf16x8 af[4], bfr[4];
      #pragma unroll
      for (int mf = 0; mf < 4; ++mf) {
        int row = o_off + mf * 16 + l15;
        int g   = (ks * 4 + quad) ^ r7;
        af[mf] = *reinterpret_cast<const bf16x8*>(&Als[p][row * BK + g * 8]);
      }
      #pragma unroll
      for (int nf = 0; nf < 4; ++nf) {
        int row = b_off + nf * 16 + l15;
        int g   = (ks * 4 + quad) ^ r7;
        bfr[nf] = *reinterpret_cast<const bf16x8*>(&Bls[p][row * BK + g * 8]);
      }
      #pragma unroll
      for (int mf = 0; mf < 4; ++mf)
        #pragma unroll
        for (int nf = 0; nf < 4; ++nf)
          acc[mf][nf] = __builtin_amdgcn_mfma_f32_16x16x32_bf16(
              af[mf], bfr[nf], acc[mf][nf], 0, 0, 0);
    }

    if (m1) {
      writeB(q, (n + 1) & 1);
      if (m2) {
        asm volatile("s_waitcnt vmcnt(8) lgkmcnt(0)\n\ts_barrier" ::: "memory");
      } else {
        asm volatile("s_waitcnt vmcnt(0) lgkmcnt(0)\n\ts_barrier" ::: "memory");
      }
    }
  }

  // ---- store partial ----
  float* Pz = P + (size_t)bz * NB * OUTD_;
  #pragma unroll
  for (int mf = 0; mf < 4; ++mf)
    #pragma unroll
    for (int nf = 0; nf < 4; ++nf) {
      int bg = b0 + b_off + nf * 16 + l15;
      int og = o0 + o_off + mf * 16 + quad * 4;
      *reinterpret_cast<f32x4*>(&Pz[(size_t)bg * OUTD_ + og]) = acc[mf][nf];
    }

  // ---- split-K completion: last block of tile reduces + relu + store ----
  __threadfence();                       // release partials (device scope)
  __syncthreads();                       // all waves' stores+fences done
  if (tid == 0)
    lastFlag = (atomicAdd(&cnt[bx * 32 + by], 1) == 3);
  __syncthreads();
  if (lastFlag) {
    __threadfence();                     // acquire: invalidate local L2
    const size_t ps = (size_t)NB * OUTD_;
    #pragma unroll
    for (int mf = 0; mf < 4; ++mf)
      #pragma unroll
      for (int nf = 0; nf < 4; ++nf) {
        int bg = b0 + b_off + nf * 16 + l15;
        int og = o0 + o_off + mf * 16 + quad * 4;
        size_t base = (size_t)bg * OUTD_ + og;
        f32x4 s = *(const f32x4*)&P[base];
        s += *(const f32x4*)&P[ps + base];
        s += *(const f32x4*)&P[2 * ps + base];
        s += *(const f32x4*)&P[3 * ps + base];
        float* op = out + (size_t)bg * XCOLS + 2 + og;   // 8B-aligned only
        float2 lo, hi;
        lo.x = s[0] > 0.0f ? s[0] : 0.0f;
        lo.y = s[1] > 0.0f ? s[1] : 0.0f;
        hi.x = s[2] > 0.0f ? s[2] : 0.0f;
        hi.y = s[3] > 0.0f ? s[3] : 0.0f;
        *(float2*)op = lo;
        *(float2*)(op + 2) = hi;
      }
  }
}

// ---------------------------------------------------------------------------
extern "C" void kernel_launch(void* const* d_in, const int* in_sizes, int n_in,
                              void* d_out, int out_size, void* d_ws, size_t ws_size,
                              hipStream_t stream) {
  const float* x    = (const float*)d_in[0];   // 4096 x 514
  const float* W    = (const float*)d_in[1];   // 512 x 512 x 25
  const float* bias = (const float*)d_in[2];   // 512 x 25
  float* out = (float*)d_out;
  char* ws = (char*)d_ws;

  // ws layout (bytes):
  //   XFb 4,194,304 | Wt 13,172,736 | kb 409,600 | P 33,554,432 | cnt 512
  const size_t xfb_off = 0;
  const size_t wt_off  = 4194304;
  const size_t kb_off  = wt_off + (size_t)OUTD_ * KT2 * 2;   // 17,367,040
  const size_t p_off   = kb_off + 409600;                     // 17,776,640
  const size_t cnt_off = p_off + (size_t)NB * OUTD_ * 4 * 4;  // 51,331,072
  unsigned short* XFb = (unsigned short*)(ws + xfb_off);
  unsigned short* Wt  = (unsigned short*)(ws + wt_off);
  float* kb           = (float*)(ws + kb_off);
  float* P            = (float*)(ws + p_off);
  int* cnt            = (int*)(ws + cnt_off);

  prep_all_kernel<<<2176, 256, 0, stream>>>(x, W, bias, XFb, kb, Wt, cnt, out);
  gemm_fused3_kernel<<<512, 256, 0, stream>>>(Wt, XFb, kb, P, out, cnt);
}

// Round 10
// 165.816 us; speedup vs baseline: 18.6934x; 18.6934x over previous
//
#include <hip/hip_runtime.h>
#include <hip/hip_bf16.h>
#include <string.h>

// Problem constants
#define NB    4096      // batch rows
#define IND_  512       // feature dim
#define OUTD_ 512       // output dim (GEMM M, "o")
#define XCOLS 514       // P + IND
#define ND    25        // D^P
#define KTOT  12800     // IND_*ND
#define KT2   12864     // KTOT + 64-col bias tail

// GEMM tiling
#define BM 128
#define BN 128
#define BK 64

typedef float  f32x4  __attribute__((ext_vector_type(4)));
typedef __bf16 bf16x8 __attribute__((ext_vector_type(8)));
typedef unsigned short u16x8 __attribute__((ext_vector_type(8)));
typedef unsigned int   u32x4 __attribute__((ext_vector_type(4)));

__device__ __forceinline__ unsigned short f2bf(float f) {
  unsigned int x = __float_as_uint(f);
  return (unsigned short)((x + 0x7fffu + ((x >> 16) & 1u)) >> 16);
}

__device__ __forceinline__ float basis_f(float t, int j) {
  switch (j) {
    case 0: return 1.0f;
    case 1: return t;
    case 2: return t * t;
    case 3: { float r = t - 0.33f; r = r > 0.0f ? r : 0.0f; return r * r; }
    default:{ float r = t - 0.66f; r = r > 0.0f ? r : 0.0f; return r * r; }
  }
}

__device__ __forceinline__ void gload_lds16(const void* g, void* l) {
  __builtin_amdgcn_global_load_lds(
      (const __attribute__((address_space(1))) void*)g,
      (__attribute__((address_space(3))) void*)l, 16, 0, 0);
}

// ---------------------------------------------------------------------------
// prep_all: ONE dispatch.
//   blocks [0,1024):    prep_b — wave per row b: Bp[b][d*512+i]=bf16(kb_d*xf_i)
//                       + bias-tail cols Bp[b][12800+d]=bf16(kb_d) + out[b][0:2]
//                       (each wave recomputes its row's kb from x directly —
//                        no cross-block dependency, so this fuses)
//   blocks [1024,2048): prep_w — W[i,o,d] fp32 -> Wt[o][d*512+i] bf16 (stride KT2)
//   blocks [2048,2176): Wt bias K-tail: Wt[o][12800+t] = bias[o][t]
// NOTE: kernel-level split (R9's in-gemm __threadfence/atomic completion
// caused a device-wide L2-flush storm: MfmaUtil 0.7%, 3.1ms. Cross-block
// handoff MUST be a kernel boundary on CDNA4.)
// ---------------------------------------------------------------------------
#define PWI 32
#define PWO 8
#define PWC (PWO * ND)   // 200
#define PWP 208
#define OLS 36

__global__ __launch_bounds__(256) void prep_all_kernel(
    const float* __restrict__ x, const float* __restrict__ W,
    const float* __restrict__ bias, unsigned short* __restrict__ Bp,
    unsigned short* __restrict__ Wt, float* __restrict__ out)
{
  __shared__ float tile[PWI * PWP];
  __shared__ unsigned short out_ls[PWC * OLS];
  const int bid = blockIdx.x;
  const int tid = threadIdx.x;

  if (bid < 1024) {
    // ---- prep_b: wave w handles row b ----
    const int b    = bid * 4 + (tid >> 6);
    const int lane = tid & 63;
    const float* xr = x + (size_t)b * XCOLS;

    // xf: 8 consecutive features per lane (base +2 floats -> 8B aligned)
    const float* fp = xr + 2 + lane * 8;
    float2 a0 = *(const float2*)(fp + 0);
    float2 a1 = *(const float2*)(fp + 2);
    float2 a2 = *(const float2*)(fp + 4);
    float2 a3 = *(const float2*)(fp + 6);
    float xf[8] = {a0.x, a0.y, a1.x, a1.y, a2.x, a2.y, a3.x, a3.y};

    float t0 = xr[0], t1 = xr[1];
    float b1[5], b2[5];
    #pragma unroll
    for (int j = 0; j < 5; ++j) { b1[j] = basis_f(t0, j); b2[j] = basis_f(t1, j); }

    unsigned short* Brow = Bp + (size_t)b * KT2;
    #pragma unroll
    for (int d = 0; d < ND; ++d) {
      float kv = b1[d / 5] * b2[d % 5];
      u16x8 pk;
      #pragma unroll
      for (int e = 0; e < 8; ++e) pk[e] = f2bf(xf[e] * kv);
      *reinterpret_cast<u16x8*>(Brow + d * IND_ + lane * 8) = pk;
    }
    // bias-tail cols: B[b][12800+t] = kb[b,t] (t<25) else 0
    {
      int d1 = lane / 5, d2 = lane - d1 * 5;
      unsigned short v = (lane < ND) ? f2bf(basis_f(t0, d1) * basis_f(t1, d2))
                                     : (unsigned short)0;
      Brow[KTOT + lane] = v;
    }
    if (lane < 2) out[(size_t)b * XCOLS + lane] = (lane == 0) ? t0 : t1;
  } else if (bid < 2048) {
    // ---- prep_w ----
    const int pw = bid - 1024;
    const int i0 = (pw & 15) * PWI;
    const int o0 = (pw >> 4) * PWO;

    for (int idx = tid; idx < PWI * (PWC / 4); idx += 256) {
      int il = idx / (PWC / 4);
      int c4 = idx - il * (PWC / 4);
      float4 v = *(const float4*)(W + ((size_t)(i0 + il) * OUTD_ + o0) * ND + c4 * 4);
      *(float4*)&tile[il * PWP + c4 * 4] = v;
    }
    __syncthreads();
    if (tid < PWC) {
      #pragma unroll
      for (int j = 0; j < PWI / 8; ++j) {
        u16x8 pk;
        #pragma unroll
        for (int jj = 0; jj < 8; ++jj)
          pk[jj] = f2bf(tile[(j * 8 + jj) * PWP + tid]);
        *reinterpret_cast<u16x8*>(&out_ls[tid * OLS + j * 8]) = pk;
      }
    }
    __syncthreads();
    for (int g = tid; g < PWC * (PWI / 8); g += 256) {
      int c  = g >> 2;
      int ig = g & 3;
      int d  = c % 25;
      int o_l = c / 25;
      u16x8 v = *reinterpret_cast<const u16x8*>(&out_ls[c * OLS + ig * 8]);
      size_t rowb = (size_t)(o0 + o_l) * KT2 + (size_t)d * IND_ + i0;
      *reinterpret_cast<u16x8*>(Wt + rowb + ig * 8) = v;
    }
  } else {
    // ---- Wt bias K-tail ----
    const int pt  = bid - 2048;          // [0,128)
    const int idx = pt * 256 + tid;      // < 512*64
    const int o = idx >> 6;
    const int t = idx & 63;
    Wt[(size_t)o * KT2 + KTOT + t] =
        (t < ND) ? f2bf(bias[o * ND + t]) : (unsigned short)0;
  }
}

// ---------------------------------------------------------------------------
// gemm_big: C[o][b] = sum_k Wt[o][k] * Bp[b][k], K=12864 (bias in tail),
// split-K 4 (split 3 takes the 64-col tail).  EXACT round-3 structure
// (measured 64.7us, replay-stable): both operands async global_load_lds x16,
// 2 __syncthreads per K-iter (compiler inserts the vmcnt(0) drain), swizzled
// granules (0 bank conflicts), XCD-swizzled block map, plain partial store.
// __launch_bounds__(256,2): round-2/6 lesson — must bound, but not tighter.
// ---------------------------------------------------------------------------
__global__ __launch_bounds__(256, 2) void gemm_big_kernel(
    const unsigned short* __restrict__ Wt, const unsigned short* __restrict__ Bp,
    float* __restrict__ P)
{
  __shared__ unsigned short Als[BM * BK];   // 16 KB
  __shared__ unsigned short Bls[BN * BK];   // 16 KB

  const int tid  = threadIdx.x;
  const int lane = tid & 63;
  const int w    = tid >> 6;
  const int l15  = lane & 15;
  const int quad = lane >> 4;

  // R3-proven XCD mapping: 512 blocks, id%8 = XCD
  const int id  = blockIdx.x;
  const int xcd = id & 7;
  const int j   = id >> 3;              // [0,64)
  const int bx  = j & 3;                // o-tile
  const int pg  = xcd * 16 + (j >> 2);  // [0,128): (b-tile, split)
  const int by  = pg & 31;
  const int bz  = pg >> 5;              // split [0,4)

  const int o0 = bx * BM;
  const int b0 = by * BN;
  const int ks_begin = bz * 3200;
  const int ks_end   = (bz == 3) ? KT2 : ks_begin + 3200;

  const int o_off = (w & 1) * 64;
  const int b_off = (w >> 1) * 64;
  const int srow  = lane >> 3;
  const int scol  = ((lane & 7) ^ srow) * 8;   // swizzled source granule
  const int r7    = l15 & 7;

  f32x4 acc[4][4];
  #pragma unroll
  for (int i = 0; i < 4; ++i)
    #pragma unroll
    for (int jj = 0; jj < 4; ++jj) acc[i][jj] = (f32x4)0.0f;

  for (int k0 = ks_begin; k0 < ks_end; k0 += BK) {
    #pragma unroll
    for (int c = 0; c < 4; ++c) {
      int chunk = w * 4 + c;
      int r = chunk * 8 + srow;
      gload_lds16(Wt + (size_t)(o0 + r) * KT2 + k0 + scol, &Als[chunk * 512]);
      gload_lds16(Bp + (size_t)(b0 + r) * KT2 + k0 + scol, &Bls[chunk * 512]);
    }
    __syncthreads();

    #pragma unroll
    for (int ks = 0; ks < 2; ++ks) {
      bf16x8 af[4], bfr[4];
      #pragma unroll
      for (int mf = 0; mf < 4; ++mf) {
        int row = o_off + mf * 16 + l15;
        int g   = (ks * 4 + quad) ^ r7;
        af[mf] = *reinterpret_cast<const bf16x8*>(&Als[row * BK + g * 8]);
      }
      #pragma unroll
      for (int nf = 0; nf < 4; ++nf) {
        int row = b_off + nf * 16 + l15;
        int g   = (ks * 4 + quad) ^ r7;
        bfr[nf] = *reinterpret_cast<const bf16x8*>(&Bls[row * BK + g * 8]);
      }
      #pragma unroll
      for (int mf = 0; mf < 4; ++mf)
        #pragma unroll
        for (int nf = 0; nf < 4; ++nf)
          acc[mf][nf] = __builtin_amdgcn_mfma_f32_16x16x32_bf16(
              af[mf], bfr[nf], acc[mf][nf], 0, 0, 0);
    }
    __syncthreads();
  }

  float* Pz = P + (size_t)bz * NB * OUTD_;
  #pragma unroll
  for (int mf = 0; mf < 4; ++mf)
    #pragma unroll
    for (int nf = 0; nf < 4; ++nf) {
      int bg = b0 + b_off + nf * 16 + l15;
      int og = o0 + o_off + mf * 16 + quad * 4;
      *reinterpret_cast<f32x4*>(&Pz[(size_t)bg * OUTD_ + og]) = acc[mf][nf];
    }
}

// ---------------------------------------------------------------------------
// epilogue: out[b][2+o] = relu(P0+P1+P2+P3)   (bias already in GEMM K-tail)
// Separate kernel = the cheap cross-block fence (R9 lesson).
// ---------------------------------------------------------------------------
__global__ __launch_bounds__(256) void epilogue_kernel(
    const float* __restrict__ P, float* __restrict__ out)
{
  const int idx = blockIdx.x * 256 + threadIdx.x;   // < 4096*512
  const int b = idx >> 9;
  const int o = idx & 511;
  const size_t stride = (size_t)NB * OUTD_;
  float s = P[idx] + P[stride + idx] + P[2 * stride + idx] + P[3 * stride + idx];
  out[(size_t)b * XCOLS + 2 + o] = s > 0.0f ? s : 0.0f;
}

// ---------------------------------------------------------------------------
extern "C" void kernel_launch(void* const* d_in, const int* in_sizes, int n_in,
                              void* d_out, int out_size, void* d_ws, size_t ws_size,
                              hipStream_t stream) {
  const float* x    = (const float*)d_in[0];   // 4096 x 514
  const float* W    = (const float*)d_in[1];   // 512 x 512 x 25
  const float* bias = (const float*)d_in[2];   // 512 x 25
  float* out = (float*)d_out;
  char* ws = (char*)d_ws;

  // ws layout (bytes):
  //   Bp 4096*12864*2 = 105,381,888 | Wt 512*12864*2 = 13,172,736
  //   P  4*4096*512*4 =  33,554,432       total 152,109,056
  const size_t bp_off = 0;
  const size_t wt_off = (size_t)NB * KT2 * 2;            // 105,381,888
  const size_t p_off  = wt_off + (size_t)OUTD_ * KT2 * 2; // 118,554,624
  unsigned short* Bp = (unsigned short*)(ws + bp_off);
  unsigned short* Wt = (unsigned short*)(ws + wt_off);
  float* P           = (float*)(ws + p_off);

  prep_all_kernel<<<2176, 256, 0, stream>>>(x, W, bias, Bp, Wt, out);
  gemm_big_kernel<<<512, 256, 0, stream>>>(Wt, Bp, P);
  epilogue_kernel<<<(NB * OUTD_) / 256, 256, 0, stream>>>(P, out);
}

// Round 11
// 151.610 us; speedup vs baseline: 20.4451x; 1.0937x over previous
//
#include <hip/hip_runtime.h>
#include <hip/hip_bf16.h>
#include <string.h>

// Problem constants
#define NB    4096      // batch rows
#define IND_  512       // feature dim
#define OUTD_ 512       // output dim (GEMM M, "o")
#define XCOLS 514       // P + IND
#define ND    25        // D^P
#define KTOT  12800     // IND_*ND
#define KT2   12864     // KTOT + 64-col bias tail

// GEMM tiling
#define BM 128
#define BN 128
#define BK 64

typedef float  f32x4  __attribute__((ext_vector_type(4)));
typedef __bf16 bf16x8 __attribute__((ext_vector_type(8)));
typedef unsigned short u16x8 __attribute__((ext_vector_type(8)));

__device__ __forceinline__ unsigned short f2bf(float f) {
  unsigned int x = __float_as_uint(f);
  return (unsigned short)((x + 0x7fffu + ((x >> 16) & 1u)) >> 16);
}

__device__ __forceinline__ float basis_f(float t, int j) {
  switch (j) {
    case 0: return 1.0f;
    case 1: return t;
    case 2: return t * t;
    case 3: { float r = t - 0.33f; r = r > 0.0f ? r : 0.0f; return r * r; }
    default:{ float r = t - 0.66f; r = r > 0.0f ? r : 0.0f; return r * r; }
  }
}

__device__ __forceinline__ void gload_lds16(const void* g, void* l) {
  __builtin_amdgcn_global_load_lds(
      (const __attribute__((address_space(1))) void*)g,
      (__attribute__((address_space(3))) void*)l, 16, 0, 0);
}

// ---------------------------------------------------------------------------
// prep_all: ONE dispatch.
//   [0,1024):    prep_x — wave per row b: XFb[b][i] bf16, kb[b][25] fp32,
//                kbT[b][64] bf16 (bias-tail B operand), out[b][0:2]
//   [1024,2048): prep_w — W[i,o,d] fp32 -> Wt[o][d*512+i] bf16 (stride KT2)
//   [2048,2176): Wt bias K-tail: Wt[o][12800+t] = bias[o][t]
// (R9 lesson: cross-block handoff must be a kernel boundary on CDNA4 —
//  in-gemm threadfence/atomic completion caused a device-wide L2-flush storm.)
// ---------------------------------------------------------------------------
#define PWI 32
#define PWO 8
#define PWC (PWO * ND)   // 200
#define PWP 208
#define OLS 36

__global__ __launch_bounds__(256) void prep_all_kernel(
    const float* __restrict__ x, const float* __restrict__ W,
    const float* __restrict__ bias, unsigned short* __restrict__ XFb,
    float* __restrict__ kb, unsigned short* __restrict__ kbT,
    unsigned short* __restrict__ Wt, float* __restrict__ out)
{
  __shared__ float tile[PWI * PWP];
  __shared__ unsigned short out_ls[PWC * OLS];
  const int bid = blockIdx.x;
  const int tid = threadIdx.x;

  if (bid < 1024) {
    // ---- prep_x ----
    const int b    = bid * 4 + (tid >> 6);
    const int lane = tid & 63;
    const float* xr = x + (size_t)b * XCOLS;

    const float* fp = xr + 2 + lane * 8;
    float2 a0 = *(const float2*)(fp + 0);
    float2 a1 = *(const float2*)(fp + 2);
    float2 a2 = *(const float2*)(fp + 4);
    float2 a3 = *(const float2*)(fp + 6);
    u16x8 pk;
    pk[0] = f2bf(a0.x); pk[1] = f2bf(a0.y); pk[2] = f2bf(a1.x); pk[3] = f2bf(a1.y);
    pk[4] = f2bf(a2.x); pk[5] = f2bf(a2.y); pk[6] = f2bf(a3.x); pk[7] = f2bf(a3.y);
    *reinterpret_cast<u16x8*>(XFb + (size_t)b * IND_ + lane * 8) = pk;

    float t0 = xr[0], t1 = xr[1];
    if (lane < 2) out[(size_t)b * XCOLS + lane] = (lane == 0) ? t0 : t1;
    int d1 = lane / 5, d2 = lane - d1 * 5;
    float kv = basis_f(t0, d1) * basis_f(t1, d2);
    if (lane < ND) kb[(size_t)b * ND + lane] = kv;
    kbT[(size_t)b * 64 + lane] = (lane < ND) ? f2bf(kv) : (unsigned short)0;
  } else if (bid < 2048) {
    // ---- prep_w ----
    const int pw = bid - 1024;
    const int i0 = (pw & 15) * PWI;
    const int o0 = (pw >> 4) * PWO;

    for (int idx = tid; idx < PWI * (PWC / 4); idx += 256) {
      int il = idx / (PWC / 4);
      int c4 = idx - il * (PWC / 4);
      float4 v = *(const float4*)(W + ((size_t)(i0 + il) * OUTD_ + o0) * ND + c4 * 4);
      *(float4*)&tile[il * PWP + c4 * 4] = v;
    }
    __syncthreads();
    if (tid < PWC) {
      #pragma unroll
      for (int j = 0; j < PWI / 8; ++j) {
        u16x8 pk;
        #pragma unroll
        for (int jj = 0; jj < 8; ++jj)
          pk[jj] = f2bf(tile[(j * 8 + jj) * PWP + tid]);
        *reinterpret_cast<u16x8*>(&out_ls[tid * OLS + j * 8]) = pk;
      }
    }
    __syncthreads();
    for (int g = tid; g < PWC * (PWI / 8); g += 256) {
      int c  = g >> 2;
      int ig = g & 3;
      int d  = c % 25;
      int o_l = c / 25;
      u16x8 v = *reinterpret_cast<const u16x8*>(&out_ls[c * OLS + ig * 8]);
      size_t rowb = (size_t)(o0 + o_l) * KT2 + (size_t)d * IND_ + i0;
      *reinterpret_cast<u16x8*>(Wt + rowb + ig * 8) = v;
    }
  } else {
    // ---- Wt bias K-tail ----
    const int pt  = bid - 2048;          // [0,128)
    const int idx = pt * 256 + tid;      // < 512*64
    const int o = idx >> 6;
    const int t = idx & 63;
    Wt[(size_t)o * KT2 + KTOT + t] =
        (t < ND) ? f2bf(bias[o * ND + t]) : (unsigned short)0;
  }
}

// ---------------------------------------------------------------------------
// gemm_phase: C[o][b] = sum_d kb[b,d]*(sum_i Wt_d[o,i]*xf[b,i]) + bias-tail.
// Same 2-barrier K-loop as R10's 65us gemm (global_load_lds x16 both sides,
// swizzled granules, XCD map, (256,2)), but B streams from the L2-resident
// XFb (4MB) instead of a 105MB materialized Bp.  kb-scale applied at PHASE
// BOUNDARIES in registers: track cur_d; on change, fin += kv*acc, acc=0.
// Split-K by K-ITERS ({50,50,50,51} incl bias iter) — splits may start/end
// mid-phase (linearity: partial-K acc scaled by kv sums correctly).
// Bias iter (k0=12800): A = Wt tail cols (same addressing), B = kbT[b][64]
// (row stride 64), kv = 1.
// ---------------------------------------------------------------------------
__global__ __launch_bounds__(256, 2) void gemm_phase_kernel(
    const unsigned short* __restrict__ Wt, const unsigned short* __restrict__ XFb,
    const float* __restrict__ kb, const unsigned short* __restrict__ kbT,
    float* __restrict__ P)
{
  __shared__ unsigned short Als[BM * BK];   // 16 KB
  __shared__ unsigned short Bls[BN * BK];   // 16 KB

  const int tid  = threadIdx.x;
  const int lane = tid & 63;
  const int w    = tid >> 6;
  const int l15  = lane & 15;
  const int quad = lane >> 4;

  // R3-proven XCD mapping: 512 blocks, id%8 = XCD
  const int id  = blockIdx.x;
  const int xcd = id & 7;
  const int j   = id >> 3;              // [0,64)
  const int bx  = j & 3;                // o-tile
  const int pg  = xcd * 16 + (j >> 2);  // [0,128): (b-tile, split)
  const int by  = pg & 31;
  const int bz  = pg >> 5;              // split [0,4)

  const int o0 = bx * BM;
  const int b0 = by * BN;
  const int ks_begin = bz * 3200;
  const int ks_end   = (bz == 3) ? KT2 : ks_begin + 3200;

  const int o_off = (w & 1) * 64;
  const int b_off = (w >> 1) * 64;
  const int srow  = lane >> 3;
  const int scol  = ((lane & 7) ^ srow) * 8;   // swizzled source granule
  const int r7    = l15 & 7;

  f32x4 acc[4][4], fin[4][4];
  #pragma unroll
  for (int i = 0; i < 4; ++i)
    #pragma unroll
    for (int jj = 0; jj < 4; ++jj) { acc[i][jj] = (f32x4)0.0f; fin[i][jj] = (f32x4)0.0f; }

  float kv[4] = {1.0f, 1.0f, 1.0f, 1.0f};
  int cur_d = -1;

  for (int k0 = ks_begin; k0 < ks_end; k0 += BK) {
    const int d = k0 >> 9;            // 25 => bias tail
    if (d != cur_d) {
      if (cur_d >= 0) {
        #pragma unroll
        for (int nf = 0; nf < 4; ++nf)
          #pragma unroll
          for (int mf = 0; mf < 4; ++mf)
            #pragma unroll
            for (int r = 0; r < 4; ++r) {
              fin[mf][nf][r] += kv[nf] * acc[mf][nf][r];
              acc[mf][nf][r] = 0.0f;
            }
      }
      cur_d = d;
      if (d < ND) {
        #pragma unroll
        for (int nf = 0; nf < 4; ++nf)
          kv[nf] = kb[(size_t)(b0 + b_off + nf * 16 + l15) * ND + d];
      } else {
        #pragma unroll
        for (int nf = 0; nf < 4; ++nf) kv[nf] = 1.0f;
      }
    }

    // stage A + B (async DMA, swizzle on SOURCE address)
    #pragma unroll
    for (int c = 0; c < 4; ++c) {
      int chunk = w * 4 + c;
      int r = chunk * 8 + srow;
      gload_lds16(Wt + (size_t)(o0 + r) * KT2 + k0 + scol, &Als[chunk * 512]);
      const unsigned short* gb = (d < ND)
          ? XFb + (size_t)(b0 + r) * IND_ + (k0 & 511) + scol
          : kbT + (size_t)(b0 + r) * 64 + scol;
      gload_lds16(gb, &Bls[chunk * 512]);
    }
    __syncthreads();

    #pragma unroll
    for (int ks = 0; ks < 2; ++ks) {
      bf16x8 af[4], bfr[4];
      #pragma unroll
      for (int mf = 0; mf < 4; ++mf) {
        int row = o_off + mf * 16 + l15;
        int g   = (ks * 4 + quad) ^ r7;
        af[mf] = *reinterpret_cast<const bf16x8*>(&Als[row * BK + g * 8]);
      }
      #pragma unroll
      for (int nf = 0; nf < 4; ++nf) {
        int row = b_off + nf * 16 + l15;
        int g   = (ks * 4 + quad) ^ r7;
        bfr[nf] = *reinterpret_cast<const bf16x8*>(&Bls[row * BK + g * 8]);
      }
      #pragma unroll
      for (int mf = 0; mf < 4; ++mf)
        #pragma unroll
        for (int nf = 0; nf < 4; ++nf)
          acc[mf][nf] = __builtin_amdgcn_mfma_f32_16x16x32_bf16(
              af[mf], bfr[nf], acc[mf][nf], 0, 0, 0);
    }
    __syncthreads();
  }

  // final flush
  #pragma unroll
  for (int nf = 0; nf < 4; ++nf)
    #pragma unroll
    for (int mf = 0; mf < 4; ++mf)
      #pragma unroll
      for (int r = 0; r < 4; ++r)
        fin[mf][nf][r] += kv[nf] * acc[mf][nf][r];

  float* Pz = P + (size_t)bz * NB * OUTD_;
  #pragma unroll
  for (int mf = 0; mf < 4; ++mf)
    #pragma unroll
    for (int nf = 0; nf < 4; ++nf) {
      int bg = b0 + b_off + nf * 16 + l15;
      int og = o0 + o_off + mf * 16 + quad * 4;
      *reinterpret_cast<f32x4*>(&Pz[(size_t)bg * OUTD_ + og]) = fin[mf][nf];
    }
}

// ---------------------------------------------------------------------------
// epilogue: out[b][2+o..2+o+1] = relu(P0+P1+P2+P3)  (bias already in K-tail)
// float2-vectorized; separate kernel = the cheap cross-block fence (R9).
// ---------------------------------------------------------------------------
__global__ __launch_bounds__(256) void epilogue_kernel(
    const float* __restrict__ P, float* __restrict__ out)
{
  const int idx = (blockIdx.x * 256 + threadIdx.x) * 2;   // < 4096*512
  const int b = idx >> 9;
  const int o = idx & 511;
  const size_t stride = (size_t)NB * OUTD_;
  float2 s0 = *(const float2*)&P[idx];
  float2 s1 = *(const float2*)&P[stride + idx];
  float2 s2 = *(const float2*)&P[2 * stride + idx];
  float2 s3 = *(const float2*)&P[3 * stride + idx];
  float2 r;
  r.x = s0.x + s1.x + s2.x + s3.x;
  r.y = s0.y + s1.y + s2.y + s3.y;
  r.x = r.x > 0.0f ? r.x : 0.0f;
  r.y = r.y > 0.0f ? r.y : 0.0f;
  *(float2*)&out[(size_t)b * XCOLS + 2 + o] = r;
}

// ---------------------------------------------------------------------------
extern "C" void kernel_launch(void* const* d_in, const int* in_sizes, int n_in,
                              void* d_out, int out_size, void* d_ws, size_t ws_size,
                              hipStream_t stream) {
  const float* x    = (const float*)d_in[0];   // 4096 x 514
  const float* W    = (const float*)d_in[1];   // 512 x 512 x 25
  const float* bias = (const float*)d_in[2];   // 512 x 25
  float* out = (float*)d_out;
  char* ws = (char*)d_ws;

  // ws layout (bytes):
  //   XFb 4,194,304 | Wt 13,172,736 | kb 409,600 | kbT 524,288 | P 33,554,432
  const size_t xfb_off = 0;
  const size_t wt_off  = 4194304;
  const size_t kb_off  = wt_off + (size_t)OUTD_ * KT2 * 2;   // 17,367,040
  const size_t kbt_off = kb_off + 409600;                     // 17,776,640
  const size_t p_off   = kbt_off + (size_t)NB * 64 * 2;       // 18,300,928
  unsigned short* XFb = (unsigned short*)(ws + xfb_off);
  unsigned short* Wt  = (unsigned short*)(ws + wt_off);
  float* kb           = (float*)(ws + kb_off);
  unsigned short* kbT = (unsigned short*)(ws + kbt_off);
  float* P            = (float*)(ws + p_off);

  prep_all_kernel<<<2176, 256, 0, stream>>>(x, W, bias, XFb, kb, kbT, Wt, out);
  gemm_phase_kernel<<<512, 256, 0, stream>>>(Wt, XFb, kb, kbT, P);
  epilogue_kernel<<<(NB * OUTD_) / 512, 256, 0, stream>>>(P, out);
}